// Round 7
// baseline (101.654 us; speedup 1.0000x reference)
//
#include <hip/hip_runtime.h>

#define Bn 8
#define Sn 2048
#define Cn 768
#define Hn 64
#define BS (Bn * Sn)

typedef __attribute__((ext_vector_type(8))) short bf16x8;
typedef __attribute__((ext_vector_type(4))) float f32x4;

__device__ __forceinline__ unsigned short f2bf(float x) {
  unsigned int u = __builtin_bit_cast(unsigned int, x);
  u += 0x7FFFu + ((u >> 16) & 1u);
  return (unsigned short)(u >> 16);
}

// ---------------- kernel 0: W convert + transpose: W[c][h] f32 -> Wt[h][c] bf16 ----------------
__global__ __launch_bounds__(256) void wconv(const float* __restrict__ Wq,
                                             const float* __restrict__ Wk,
                                             const float* __restrict__ Wv,
                                             unsigned short* __restrict__ Wt) {
  int idx = blockIdx.x * 256 + threadIdx.x;      // 3*768*64 = 147456 total
  int mat = idx / (Cn * Hn);
  int rem = idx - mat * (Cn * Hn);
  int c = rem / Hn, h = rem - c * Hn;
  const float* W = (mat == 0) ? Wq : (mat == 1) ? Wk : Wv;
  Wt[mat * (Hn * Cn) + h * Cn + c] = f2bf(W[rem]);
}

// ---------------- kernel 1: projection, contiguous one-touch X ----------------
// Block = 64 rows x 64 cols x K=768. Phase 1: stage the block's X region
// (196608 CONTIGUOUS bytes, lane-consecutive float4s = 1KB/instr) into a 96KB
// swizzled bf16 LDS tile (12288 float4s = 48 iters x 256 thr — R6 bug was 12).
// Phase 2: 12 K-chunks, W double-buffered (reg prefetch, write-late, 1
// barrier/chunk), 8 MFMA each. 768 blocks, 1 block/CU, 3 even rounds.
__global__ __launch_bounds__(256) void proj(const float* __restrict__ q,
                                            const float* __restrict__ k,
                                            const float* __restrict__ v,
                                            const float* __restrict__ bq,
                                            const float* __restrict__ bk,
                                            const float* __restrict__ bv,
                                            const unsigned short* __restrict__ Wt,
                                            unsigned short* __restrict__ qi,
                                            unsigned short* __restrict__ ki,
                                            unsigned short* __restrict__ vi) {
  const int mat  = blockIdx.x >> 8;
  const int row0 = (blockIdx.x & 255) * 64;
  const float* X    = (mat == 0) ? q  : (mat == 1) ? k  : v;
  const float* bias = (mat == 0) ? bq : (mat == 1) ? bk : bv;
  unsigned short* Y = (mat == 0) ? qi : (mat == 1) ? ki : vi;
  const unsigned short* Wm = Wt + mat * (Hn * Cn);
  const float scale = (mat == 0) ? 0.03608439182435161f : 1.0f;  // 1/sqrt(768) folded into qi

  __shared__ __align__(16) unsigned char Xs[64 * 1536];      // [64 rows][768 bf16], swizzled
  __shared__ __align__(16) unsigned char Ws[2][64 * 128];    // W chunk double buffer

  const int tid  = threadIdx.x;
  const int lane = tid & 63;
  const int w    = tid >> 6;
  const int col  = lane & 15;
  const int grp  = lane >> 4;

  // ---- Phase 1: contiguous X stage (12288 float4s, thread-consecutive) ----
  const float* Xblk = X + (size_t)row0 * Cn;
#pragma unroll 8
  for (int i = 0; i < 48; ++i) {
    int f   = i * 256 + tid;        // float4 index in block region (0..12287)
    int row = f / 192;              // 192 float4 per row (768 f32)
    int cf4 = f - row * 192;
    float4 xv = *(const float4*)(Xblk + (size_t)f * 4);
    ushort4 hv;
    hv.x = f2bf(xv.x); hv.y = f2bf(xv.y); hv.z = f2bf(xv.z); hv.w = f2bf(xv.w);
    *(ushort4*)(Xs + row * 1536 + ((cf4 * 8) ^ ((row & 7) << 4))) = hv;
  }
  // stage W chunk 0
  const int wr_ = tid >> 2;   // output col h 0..63
  const int wp_ = tid & 3;    // 16-elem piece
  const unsigned short* Wrow = Wm + (size_t)wr_ * Cn + wp_ * 16;
  const int wo0 = wr_ * 128 + ((wp_ * 32) ^ ((wr_ & 7) << 4));
  const int wo1 = wr_ * 128 + (((wp_ * 32) + 16) ^ ((wr_ & 7) << 4));
  *(uint4*)(Ws[0] + wo0) = *(const uint4*)(Wrow);
  *(uint4*)(Ws[0] + wo1) = *(const uint4*)(Wrow + 8);
  __syncthreads();

  // ---- Phase 2: K-chunk loop ----
  f32x4 acc[4] = {};
  const int rloc = w * 16 + col;
  const int xswz = (rloc & 7) << 4;

  for (int c = 0; c < 12; ++c) {
    // prefetch next W chunk to regs (issue before MFMAs)
    uint4 wra, wrb;
    if (c < 11) {
      wra = *(const uint4*)(Wrow + (c + 1) * 64);
      wrb = *(const uint4*)(Wrow + (c + 1) * 64 + 8);
    }
    const unsigned char* Wb = Ws[c & 1];
#pragma unroll
    for (int ks = 0; ks < 2; ++ks) {
      bf16x8 a = *(const bf16x8*)(Xs + rloc * 1536 + ((c * 128 + ks * 64 + grp * 16) ^ xswz));
#pragma unroll
      for (int nf = 0; nf < 4; ++nf) {
        int wc = nf * 16 + col;
        bf16x8 bfr = *(const bf16x8*)(Wb + wc * 128 + ((ks * 64 + grp * 16) ^ ((wc & 7) << 4)));
        acc[nf] = __builtin_amdgcn_mfma_f32_16x16x32_bf16(a, bfr, acc[nf], 0, 0, 0);
      }
    }
    if (c < 11) {
      // write next chunk into the other buffer (its last readers synced a barrier ago)
      unsigned char* Wn = Ws[(c + 1) & 1];
      *(uint4*)(Wn + wo0) = wra;
      *(uint4*)(Wn + wo1) = wrb;
      __syncthreads();
    }
  }

  // epilogue: D layout col = lane&15, row = grp*4 + reg
#pragma unroll
  for (int nf = 0; nf < 4; ++nf) {
    int h = nf * 16 + col;
    float bb = bias[h];
#pragma unroll
    for (int r2 = 0; r2 < 4; ++r2) {
      int row = row0 + w * 16 + grp * 4 + r2;
      Y[(size_t)row * Hn + h] = f2bf((acc[nf][r2] + bb) * scale);
    }
  }
}

// ---------------- kernel 2: flash attention, optional KV split ----------------
template <int SPLIT>
__global__ __launch_bounds__(256) void attn(const unsigned short* __restrict__ qi,
                                            const unsigned short* __restrict__ ki,
                                            const unsigned short* __restrict__ vi,
                                            float* __restrict__ pacc,
                                            float* __restrict__ pm,
                                            float* __restrict__ pl,
                                            float* __restrict__ out,
                                            int tpb) {
  const int bq    = blockIdx.x & 255;
  const int split = blockIdx.x >> 8;
  const int b  = bq >> 5;
  const int s0 = (bq & 31) * 64;
  const int t0 = split * tpb;
  const unsigned short* Qb = qi + ((size_t)b * Sn + s0) * Hn;
  const unsigned short* Kb = ki + (size_t)b * Sn * Hn;
  const unsigned short* Vb = vi + (size_t)b * Sn * Hn;

  __shared__ __align__(16) unsigned char Ks[64 * 128];       // [key][dim] bf16, swizzled
  __shared__ __align__(16) unsigned char Vt[64 * 128];       // [dim][key] bf16, swizzled
  __shared__ __align__(16) unsigned char Ps[4 * 16 * 128];   // per-wave [16 q][64 key] bf16

  const int tid  = threadIdx.x;
  const int lane = tid & 63;
  const int w    = tid >> 6;
  const int col  = lane & 15;
  const int grp  = lane >> 4;

  bf16x8 qa[2];
#pragma unroll
  for (int ks2 = 0; ks2 < 2; ++ks2)
    qa[ks2] = *(const bf16x8*)(Qb + (size_t)(w * 16 + col) * Hn + ks2 * 32 + grp * 8);

  f32x4 acc[4] = {};
  float m[4], l[4];
#pragma unroll
  for (int r = 0; r < 4; ++r) { m[r] = -1e30f; l[r] = 0.0f; }

  for (int t = t0; t < t0 + tpb; ++t) {
    const unsigned short* Kt = Kb + t * 64 * Hn;
    const unsigned short* Vg = Vb + t * 64 * Hn;
    __syncthreads();  // previous tile fully consumed by all waves
    {
      int kr = tid >> 2, p = tid & 3;
      const uint4* src = (const uint4*)(Kt + kr * Hn);
      uint4 a  = src[p * 2];
      uint4 b2 = src[p * 2 + 1];
      *(uint4*)(Ks + kr * 128 + ((p * 32) ^ ((kr & 7) << 4)))        = a;
      *(uint4*)(Ks + kr * 128 + (((p * 32) + 16) ^ ((kr & 7) << 4))) = b2;
    }
    {
      int kp = tid >> 3;
      int dg = tid & 7;
      uint4 v0 = *(const uint4*)(Vg + (2 * kp) * Hn + dg * 8);
      uint4 v1 = *(const uint4*)(Vg + (2 * kp + 1) * Hn + dg * 8);
      const unsigned short* a0 = (const unsigned short*)&v0;
      const unsigned short* a1 = (const unsigned short*)&v1;
#pragma unroll
      for (int j0 = 0; j0 < 8; ++j0) {
        int j = (j0 + dg) & 7;
        int d = dg * 8 + j;
        unsigned int pk = (unsigned int)a0[j] | ((unsigned int)a1[j] << 16);
        *(unsigned int*)(Vt + d * 128 + ((4 * kp) ^ ((d & 7) << 4))) = pk;
      }
    }
    __syncthreads();
    // S = Q K^T
    f32x4 sf[4] = {};
#pragma unroll
    for (int ks2 = 0; ks2 < 2; ++ks2) {
#pragma unroll
      for (int nf = 0; nf < 4; ++nf) {
        int kr = nf * 16 + col;
        bf16x8 bfr = *(const bf16x8*)(Ks + kr * 128 + ((ks2 * 64 + grp * 16) ^ ((kr & 7) << 4)));
        sf[nf] = __builtin_amdgcn_mfma_f32_16x16x32_bf16(qa[ks2], bfr, sf[nf], 0, 0, 0);
      }
    }
    // online softmax
    float mn[4], fs[4];
#pragma unroll
    for (int r = 0; r < 4; ++r) {
      float mx = fmaxf(fmaxf(sf[0][r], sf[1][r]), fmaxf(sf[2][r], sf[3][r]));
#pragma unroll
      for (int off = 1; off < 16; off <<= 1)
        mx = fmaxf(mx, __shfl_xor(mx, off, 64));
      mn[r] = fmaxf(m[r], mx);
      fs[r] = __expf(m[r] - mn[r]);
      m[r]  = mn[r];
    }
#pragma unroll
    for (int nf = 0; nf < 4; ++nf)
#pragma unroll
      for (int r = 0; r < 4; ++r)
        sf[nf][r] = __expf(sf[nf][r] - mn[r]);
#pragma unroll
    for (int r = 0; r < 4; ++r) {
      float sm = sf[0][r] + sf[1][r] + sf[2][r] + sf[3][r];
#pragma unroll
      for (int off = 1; off < 16; off <<= 1)
        sm += __shfl_xor(sm, off, 64);
      l[r] = l[r] * fs[r] + sm;
    }
#pragma unroll
    for (int nf = 0; nf < 4; ++nf) {
#pragma unroll
      for (int r = 0; r < 4; ++r) {
        acc[nf][r] *= fs[r];
        int prow = grp * 4 + r;
        int key  = nf * 16 + col;
        *(unsigned short*)(Ps + w * 2048 + prow * 128 + ((key * 2) ^ ((prow & 7) << 4))) =
            f2bf(sf[nf][r]);
      }
    }
    // per-wave Ps: no cross-wave barrier needed before PV
#pragma unroll
    for (int kk = 0; kk < 2; ++kk) {
      bf16x8 pa = *(const bf16x8*)(Ps + w * 2048 + col * 128 +
                                   ((kk * 64 + grp * 16) ^ ((col & 7) << 4)));
#pragma unroll
      for (int nf = 0; nf < 4; ++nf) {
        int dr = nf * 16 + col;
        bf16x8 bv = *(const bf16x8*)(Vt + dr * 128 + ((kk * 64 + grp * 16) ^ ((dr & 7) << 4)));
        acc[nf] = __builtin_amdgcn_mfma_f32_16x16x32_bf16(pa, bv, acc[nf], 0, 0, 0);
      }
    }
  }
  // epilogue
  if (SPLIT) {
    const size_t sb = (size_t)split * BS + (size_t)b * Sn;
#pragma unroll
    for (int nf = 0; nf < 4; ++nf) {
#pragma unroll
      for (int r = 0; r < 4; ++r) {
        int row = s0 + w * 16 + grp * 4 + r;
        pacc[(sb + row) * Hn + nf * 16 + col] = acc[nf][r];
      }
    }
    if (col == 0) {
#pragma unroll
      for (int r = 0; r < 4; ++r) {
        int row = s0 + w * 16 + grp * 4 + r;
        pm[sb + row] = m[r];
        pl[sb + row] = l[r];
      }
    }
  } else {
#pragma unroll
    for (int nf = 0; nf < 4; ++nf) {
#pragma unroll
      for (int r = 0; r < 4; ++r) {
        int row = s0 + w * 16 + grp * 4 + r;
        out[((size_t)b * Sn + row) * Hn + nf * 16 + col] = acc[nf][r] / l[r];
      }
    }
  }
}

// ---------------- kernel 3: combine attn split partials ----------------
__global__ __launch_bounds__(256) void combine(const float* __restrict__ pacc,
                                               const float* __restrict__ pm,
                                               const float* __restrict__ pl,
                                               float* __restrict__ out,
                                               int nsplit) {
  int gid = blockIdx.x * 256 + threadIdx.x;
  int gr  = gid >> 4;          // global row in [0, B*S)
  int dq  = (gid & 15) * 4;    // dim quad
  float M = -1e30f;
  for (int s = 0; s < nsplit; ++s) M = fmaxf(M, pm[(size_t)s * BS + gr]);
  float L = 0.0f;
  float4 o = make_float4(0.f, 0.f, 0.f, 0.f);
  for (int s = 0; s < nsplit; ++s) {
    float wgt = __expf(pm[(size_t)s * BS + gr] - M);
    L += pl[(size_t)s * BS + gr] * wgt;
    float4 p = *(const float4*)(pacc + ((size_t)s * BS + gr) * Hn + dq);
    o.x += p.x * wgt; o.y += p.y * wgt; o.z += p.z * wgt; o.w += p.w * wgt;
  }
  float inv = 1.0f / L;
  float4 r = make_float4(o.x * inv, o.y * inv, o.z * inv, o.w * inv);
  *(float4*)(out + (size_t)gr * Hn + dq) = r;
}

extern "C" void kernel_launch(void* const* d_in, const int* in_sizes, int n_in,
                              void* d_out, int out_size, void* d_ws, size_t ws_size,
                              hipStream_t stream) {
  const float* q  = (const float*)d_in[0];
  const float* k  = (const float*)d_in[1];
  const float* v  = (const float*)d_in[2];
  const float* Wq = (const float*)d_in[3];
  const float* bq = (const float*)d_in[4];
  const float* Wk = (const float*)d_in[5];
  const float* bk = (const float*)d_in[6];
  const float* Wv = (const float*)d_in[7];
  const float* bv = (const float*)d_in[8];
  float* out = (float*)d_out;

  unsigned short* Wt = (unsigned short*)d_ws;            // [3][64][768] bf16
  unsigned short* qi = Wt + 3 * Hn * Cn;                 // bf16, pre-scaled by 1/sqrt(C)
  unsigned short* ki = qi + (size_t)BS * Hn;
  unsigned short* vi = ki + (size_t)BS * Hn;
  float* pacc = (float*)(vi + (size_t)BS * Hn);

  const size_t base_bytes = (size_t)(3 * Hn * Cn + 3 * (size_t)BS * Hn) * 2;
  const size_t avail = (ws_size > base_bytes) ? ws_size - base_bytes : 0;

  int nsplit = 4;
  while (nsplit > 1 &&
         (size_t)nsplit * ((size_t)BS * Hn * 4 + 2 * (size_t)BS * 4) > avail)
    nsplit >>= 1;
  bool direct = ((size_t)nsplit * ((size_t)BS * Hn * 4 + 2 * (size_t)BS * 4) > avail);

  float* pm = pacc + (size_t)nsplit * BS * Hn;
  float* pl = pm + (size_t)nsplit * BS;

  wconv<<<dim3((3 * Cn * Hn) / 256), dim3(256), 0, stream>>>(Wq, Wk, Wv, Wt);
  proj<<<dim3(768), dim3(256), 0, stream>>>(q, k, v, bq, bk, bv, Wt, qi, ki, vi);
  if (direct) {
    attn<0><<<dim3(256), dim3(256), 0, stream>>>(qi, ki, vi, nullptr, nullptr, nullptr, out, 32);
  } else {
    attn<1><<<dim3(256 * nsplit), dim3(256), 0, stream>>>(qi, ki, vi, pacc, pm, pl, nullptr,
                                                          32 / nsplit);
    combine<<<dim3(BS * 16 / 256), dim3(256), 0, stream>>>(pacc, pm, pl, out, nsplit);
  }
}

// Round 8
// 91.174 us; speedup vs baseline: 1.1149x; 1.1149x over previous
//
#include <hip/hip_runtime.h>

#define Bn 8
#define Sn 2048
#define Cn 768
#define Hn 64
#define BS (Bn * Sn)

typedef __attribute__((ext_vector_type(8))) short bf16x8;
typedef __attribute__((ext_vector_type(4))) float f32x4;

__device__ __forceinline__ unsigned short f2bf(float x) {
  unsigned int u = __builtin_bit_cast(unsigned int, x);
  u += 0x7FFFu + ((u >> 16) & 1u);
  return (unsigned short)(u >> 16);
}

// async global->LDS DMA, 16B per lane; dest = wave-uniform base + lane*16 (linear)
__device__ __forceinline__ void gload_lds16(const void* g, void* l) {
  __builtin_amdgcn_global_load_lds(
      (const __attribute__((address_space(1))) unsigned int*)g,
      (__attribute__((address_space(3))) unsigned int*)l, 16, 0, 0);
}

// ---------------- kernel 0: W convert + transpose: W[c][h] f32 -> Wt[h][c] bf16 ----------------
__global__ __launch_bounds__(256) void wconv(const float* __restrict__ Wq,
                                             const float* __restrict__ Wk,
                                             const float* __restrict__ Wv,
                                             unsigned short* __restrict__ Wt) {
  int idx = blockIdx.x * 256 + threadIdx.x;      // 3*768*64 = 147456 total
  int mat = idx / (Cn * Hn);
  int rem = idx - mat * (Cn * Hn);
  int c = rem / Hn, h = rem - c * Hn;
  const float* W = (mat == 0) ? Wq : (mat == 1) ? Wk : Wv;
  Wt[mat * (Hn * Cn) + h * Cn + c] = f2bf(W[rem]);
}

// ---------------- kernel 1: projection via async global_load_lds staging ----------------
// Block = 64 rows x 64 cols, K-chunks of 64. X staged as f32 (16KB/chunk) and W bf16
// (8KB/chunk) by global_load_lds width=16, double-buffered, ONE barrier per chunk,
// stage issued after the barrier so loads fly under compute (T3-minimal, m97 pattern).
// LDS dest is linear (HW requirement) -> bank-conflict-free via SOURCE pre-swizzle:
//   X slot sidx holds (row=sidx>>4, cf4=(sidx&15)^(row&15));  read byte = row*256+((cf4w^col))*16
//   W slot sidx holds (h=sidx>>3,  p =(sidx&7)^(h&7));        read byte = h*128+((pw^(h&7)))*16
__global__ __launch_bounds__(256) void proj(const float* __restrict__ q,
                                            const float* __restrict__ k,
                                            const float* __restrict__ v,
                                            const float* __restrict__ bq,
                                            const float* __restrict__ bk,
                                            const float* __restrict__ bv,
                                            const unsigned short* __restrict__ Wt,
                                            unsigned short* __restrict__ qi,
                                            unsigned short* __restrict__ ki,
                                            unsigned short* __restrict__ vi) {
  const int mat  = blockIdx.x >> 8;
  const int row0 = (blockIdx.x & 255) * 64;
  const float* X    = (mat == 0) ? q  : (mat == 1) ? k  : v;
  const float* bias = (mat == 0) ? bq : (mat == 1) ? bk : bv;
  unsigned short* Y = (mat == 0) ? qi : (mat == 1) ? ki : vi;
  const unsigned short* Wm = Wt + mat * (Hn * Cn);
  const float scale = (mat == 0) ? 0.03608439182435161f : 1.0f;  // 1/sqrt(768) folded into qi

  __shared__ __align__(16) float          Xf[2][4096];   // 2 x 16KB: [64 rows][16 slots x 4 f32]
  __shared__ __align__(16) unsigned short Wl[2][4096];   // 2 x 8KB:  [64 h][8 slots x 8 bf16]

  const int tid  = threadIdx.x;
  const int lane = tid & 63;
  const int w    = tid >> 6;
  const int col  = lane & 15;
  const int grp  = lane >> 4;

  // per-thread pre-swizzled global source pointers (chunk 0)
  const float* xsrc[4];
#pragma unroll
  for (int j = 0; j < 4; ++j) {
    int sidx = j * 256 + tid;
    int row  = sidx >> 4;
    int cf4  = (sidx & 15) ^ (row & 15);
    xsrc[j]  = X + (size_t)(row0 + row) * Cn + cf4 * 4;
  }
  const unsigned short* wsrc[2];
#pragma unroll
  for (int j = 0; j < 2; ++j) {
    int sidx = j * 256 + tid;
    int h    = sidx >> 3;
    int pd   = (sidx & 7) ^ (h & 7);
    wsrc[j]  = Wm + (size_t)h * Cn + pd * 8;
  }

  // prologue: stage chunk 0 into buf 0
#pragma unroll
  for (int j = 0; j < 4; ++j) gload_lds16(xsrc[j], &Xf[0][(j * 256 + w * 64) * 4]);
#pragma unroll
  for (int j = 0; j < 2; ++j) gload_lds16(wsrc[j], &Wl[0][(j * 256 + w * 64) * 8]);

  f32x4 acc[4] = {};
  const int rloc = w * 16 + col;

  for (int c = 0; c < 12; ++c) {
    const int buf = c & 1;
    __syncthreads();   // drains this wave's DMAs (chunk c ready); joins waves
    if (c < 11) {      // issue chunk c+1 into the other buffer; flies under compute below
      const int nb = buf ^ 1;
#pragma unroll
      for (int j = 0; j < 4; ++j)
        gload_lds16(xsrc[j] + (c + 1) * 64, &Xf[nb][(j * 256 + w * 64) * 4]);
#pragma unroll
      for (int j = 0; j < 2; ++j)
        gload_lds16(wsrc[j] + (c + 1) * 64, &Wl[nb][(j * 256 + w * 64) * 8]);
    }
    // compute chunk c
#pragma unroll
    for (int ks = 0; ks < 2; ++ks) {
      const int cf0 = ks * 8 + grp * 2;
      float4 a0 = *(const float4*)&Xf[buf][(rloc * 16 + (cf0 ^ col)) * 4];
      float4 a1 = *(const float4*)&Xf[buf][(rloc * 16 + ((cf0 + 1) ^ col)) * 4];
      bf16x8 av;
      av[0] = (short)f2bf(a0.x); av[1] = (short)f2bf(a0.y);
      av[2] = (short)f2bf(a0.z); av[3] = (short)f2bf(a0.w);
      av[4] = (short)f2bf(a1.x); av[5] = (short)f2bf(a1.y);
      av[6] = (short)f2bf(a1.z); av[7] = (short)f2bf(a1.w);
      const int p = ks * 4 + grp;
#pragma unroll
      for (int nf = 0; nf < 4; ++nf) {
        int h = nf * 16 + col;
        bf16x8 bfr = *(const bf16x8*)&Wl[buf][(h * 8 + (p ^ (h & 7))) * 8];
        acc[nf] = __builtin_amdgcn_mfma_f32_16x16x32_bf16(av, bfr, acc[nf], 0, 0, 0);
      }
    }
  }

  // epilogue: D layout col = lane&15, row = grp*4 + reg
#pragma unroll
  for (int nf = 0; nf < 4; ++nf) {
    int h = nf * 16 + col;
    float bb = bias[h];
#pragma unroll
    for (int r2 = 0; r2 < 4; ++r2) {
      int row = row0 + w * 16 + grp * 4 + r2;
      Y[(size_t)row * Hn + h] = f2bf((acc[nf][r2] + bb) * scale);
    }
  }
}

// ---------------- kernel 2: flash attention, optional KV split ----------------
template <int SPLIT>
__global__ __launch_bounds__(256) void attn(const unsigned short* __restrict__ qi,
                                            const unsigned short* __restrict__ ki,
                                            const unsigned short* __restrict__ vi,
                                            float* __restrict__ pacc,
                                            float* __restrict__ pm,
                                            float* __restrict__ pl,
                                            float* __restrict__ out,
                                            int tpb) {
  const int bq    = blockIdx.x & 255;
  const int split = blockIdx.x >> 8;
  const int b  = bq >> 5;
  const int s0 = (bq & 31) * 64;
  const int t0 = split * tpb;
  const unsigned short* Qb = qi + ((size_t)b * Sn + s0) * Hn;
  const unsigned short* Kb = ki + (size_t)b * Sn * Hn;
  const unsigned short* Vb = vi + (size_t)b * Sn * Hn;

  __shared__ __align__(16) unsigned char Ks[64 * 128];       // [key][dim] bf16, swizzled
  __shared__ __align__(16) unsigned char Vt[64 * 128];       // [dim][key] bf16, swizzled
  __shared__ __align__(16) unsigned char Ps[4 * 16 * 128];   // per-wave [16 q][64 key] bf16

  const int tid  = threadIdx.x;
  const int lane = tid & 63;
  const int w    = tid >> 6;
  const int col  = lane & 15;
  const int grp  = lane >> 4;

  bf16x8 qa[2];
#pragma unroll
  for (int ks2 = 0; ks2 < 2; ++ks2)
    qa[ks2] = *(const bf16x8*)(Qb + (size_t)(w * 16 + col) * Hn + ks2 * 32 + grp * 8);

  f32x4 acc[4] = {};
  float m[4], l[4];
#pragma unroll
  for (int r = 0; r < 4; ++r) { m[r] = -1e30f; l[r] = 0.0f; }

  for (int t = t0; t < t0 + tpb; ++t) {
    const unsigned short* Kt = Kb + t * 64 * Hn;
    const unsigned short* Vg = Vb + t * 64 * Hn;
    __syncthreads();  // previous tile fully consumed by all waves
    {
      int kr = tid >> 2, p = tid & 3;
      const uint4* src = (const uint4*)(Kt + kr * Hn);
      uint4 a  = src[p * 2];
      uint4 b2 = src[p * 2 + 1];
      *(uint4*)(Ks + kr * 128 + ((p * 32) ^ ((kr & 7) << 4)))        = a;
      *(uint4*)(Ks + kr * 128 + (((p * 32) + 16) ^ ((kr & 7) << 4))) = b2;
    }
    {
      int kp = tid >> 3;
      int dg = tid & 7;
      uint4 v0 = *(const uint4*)(Vg + (2 * kp) * Hn + dg * 8);
      uint4 v1 = *(const uint4*)(Vg + (2 * kp + 1) * Hn + dg * 8);
      const unsigned short* a0 = (const unsigned short*)&v0;
      const unsigned short* a1 = (const unsigned short*)&v1;
#pragma unroll
      for (int j0 = 0; j0 < 8; ++j0) {
        int j = (j0 + dg) & 7;
        int d = dg * 8 + j;
        unsigned int pk = (unsigned int)a0[j] | ((unsigned int)a1[j] << 16);
        *(unsigned int*)(Vt + d * 128 + ((4 * kp) ^ ((d & 7) << 4))) = pk;
      }
    }
    __syncthreads();
    // S = Q K^T
    f32x4 sf[4] = {};
#pragma unroll
    for (int ks2 = 0; ks2 < 2; ++ks2) {
#pragma unroll
      for (int nf = 0; nf < 4; ++nf) {
        int kr = nf * 16 + col;
        bf16x8 bfr = *(const bf16x8*)(Ks + kr * 128 + ((ks2 * 64 + grp * 16) ^ ((kr & 7) << 4)));
        sf[nf] = __builtin_amdgcn_mfma_f32_16x16x32_bf16(qa[ks2], bfr, sf[nf], 0, 0, 0);
      }
    }
    // online softmax
    float mn[4], fs[4];
#pragma unroll
    for (int r = 0; r < 4; ++r) {
      float mx = fmaxf(fmaxf(sf[0][r], sf[1][r]), fmaxf(sf[2][r], sf[3][r]));
#pragma unroll
      for (int off = 1; off < 16; off <<= 1)
        mx = fmaxf(mx, __shfl_xor(mx, off, 64));
      mn[r] = fmaxf(m[r], mx);
      fs[r] = __expf(m[r] - mn[r]);
      m[r]  = mn[r];
    }
#pragma unroll
    for (int nf = 0; nf < 4; ++nf)
#pragma unroll
      for (int r = 0; r < 4; ++r)
        sf[nf][r] = __expf(sf[nf][r] - mn[r]);
#pragma unroll
    for (int r = 0; r < 4; ++r) {
      float sm = sf[0][r] + sf[1][r] + sf[2][r] + sf[3][r];
#pragma unroll
      for (int off = 1; off < 16; off <<= 1)
        sm += __shfl_xor(sm, off, 64);
      l[r] = l[r] * fs[r] + sm;
    }
#pragma unroll
    for (int nf = 0; nf < 4; ++nf) {
#pragma unroll
      for (int r = 0; r < 4; ++r) {
        acc[nf][r] *= fs[r];
        int prow = grp * 4 + r;
        int key  = nf * 16 + col;
        *(unsigned short*)(Ps + w * 2048 + prow * 128 + ((key * 2) ^ ((prow & 7) << 4))) =
            f2bf(sf[nf][r]);
      }
    }
    // per-wave Ps: no cross-wave barrier needed before PV
#pragma unroll
    for (int kk = 0; kk < 2; ++kk) {
      bf16x8 pa = *(const bf16x8*)(Ps + w * 2048 + col * 128 +
                                   ((kk * 64 + grp * 16) ^ ((col & 7) << 4)));
#pragma unroll
      for (int nf = 0; nf < 4; ++nf) {
        int dr = nf * 16 + col;
        bf16x8 bv = *(const bf16x8*)(Vt + dr * 128 + ((kk * 64 + grp * 16) ^ ((dr & 7) << 4)));
        acc[nf] = __builtin_amdgcn_mfma_f32_16x16x32_bf16(pa, bv, acc[nf], 0, 0, 0);
      }
    }
  }
  // epilogue
  if (SPLIT) {
    const size_t sb = (size_t)split * BS + (size_t)b * Sn;
#pragma unroll
    for (int nf = 0; nf < 4; ++nf) {
#pragma unroll
      for (int r = 0; r < 4; ++r) {
        int row = s0 + w * 16 + grp * 4 + r;
        pacc[(sb + row) * Hn + nf * 16 + col] = acc[nf][r];
      }
    }
    if (col == 0) {
#pragma unroll
      for (int r = 0; r < 4; ++r) {
        int row = s0 + w * 16 + grp * 4 + r;
        pm[sb + row] = m[r];
        pl[sb + row] = l[r];
      }
    }
  } else {
#pragma unroll
    for (int nf = 0; nf < 4; ++nf) {
#pragma unroll
      for (int r = 0; r < 4; ++r) {
        int row = s0 + w * 16 + grp * 4 + r;
        out[((size_t)b * Sn + row) * Hn + nf * 16 + col] = acc[nf][r] / l[r];
      }
    }
  }
}

// ---------------- kernel 3: combine attn split partials ----------------
__global__ __launch_bounds__(256) void combine(const float* __restrict__ pacc,
                                               const float* __restrict__ pm,
                                               const float* __restrict__ pl,
                                               float* __restrict__ out,
                                               int nsplit) {
  int gid = blockIdx.x * 256 + threadIdx.x;
  int gr  = gid >> 4;          // global row in [0, B*S)
  int dq  = (gid & 15) * 4;    // dim quad
  float M = -1e30f;
  for (int s = 0; s < nsplit; ++s) M = fmaxf(M, pm[(size_t)s * BS + gr]);
  float L = 0.0f;
  float4 o = make_float4(0.f, 0.f, 0.f, 0.f);
  for (int s = 0; s < nsplit; ++s) {
    float wgt = __expf(pm[(size_t)s * BS + gr] - M);
    L += pl[(size_t)s * BS + gr] * wgt;
    float4 p = *(const float4*)(pacc + ((size_t)s * BS + gr) * Hn + dq);
    o.x += p.x * wgt; o.y += p.y * wgt; o.z += p.z * wgt; o.w += p.w * wgt;
  }
  float inv = 1.0f / L;
  float4 r = make_float4(o.x * inv, o.y * inv, o.z * inv, o.w * inv);
  *(float4*)(out + (size_t)gr * Hn + dq) = r;
}

extern "C" void kernel_launch(void* const* d_in, const int* in_sizes, int n_in,
                              void* d_out, int out_size, void* d_ws, size_t ws_size,
                              hipStream_t stream) {
  const float* q  = (const float*)d_in[0];
  const float* k  = (const float*)d_in[1];
  const float* v  = (const float*)d_in[2];
  const float* Wq = (const float*)d_in[3];
  const float* bq = (const float*)d_in[4];
  const float* Wk = (const float*)d_in[5];
  const float* bk = (const float*)d_in[6];
  const float* Wv = (const float*)d_in[7];
  const float* bv = (const float*)d_in[8];
  float* out = (float*)d_out;

  unsigned short* Wt = (unsigned short*)d_ws;            // [3][64][768] bf16
  unsigned short* qi = Wt + 3 * Hn * Cn;                 // bf16, pre-scaled by 1/sqrt(C)
  unsigned short* ki = qi + (size_t)BS * Hn;
  unsigned short* vi = ki + (size_t)BS * Hn;
  float* pacc = (float*)(vi + (size_t)BS * Hn);

  const size_t base_bytes = (size_t)(3 * Hn * Cn + 3 * (size_t)BS * Hn) * 2;
  const size_t avail = (ws_size > base_bytes) ? ws_size - base_bytes : 0;

  int nsplit = 4;
  while (nsplit > 1 &&
         (size_t)nsplit * ((size_t)BS * Hn * 4 + 2 * (size_t)BS * 4) > avail)
    nsplit >>= 1;
  bool direct = ((size_t)nsplit * ((size_t)BS * Hn * 4 + 2 * (size_t)BS * 4) > avail);

  float* pm = pacc + (size_t)nsplit * BS * Hn;
  float* pl = pm + (size_t)nsplit * BS;

  wconv<<<dim3((3 * Cn * Hn) / 256), dim3(256), 0, stream>>>(Wq, Wk, Wv, Wt);
  proj<<<dim3(768), dim3(256), 0, stream>>>(q, k, v, bq, bk, bv, Wt, qi, ki, vi);
  if (direct) {
    attn<0><<<dim3(256), dim3(256), 0, stream>>>(qi, ki, vi, nullptr, nullptr, nullptr, out, 32);
  } else {
    attn<1><<<dim3(256 * nsplit), dim3(256), 0, stream>>>(qi, ki, vi, pacc, pm, pl, nullptr,
                                                          32 / nsplit);
    combine<<<dim3(BS * 16 / 256), dim3(256), 0, stream>>>(pacc, pm, pl, out, nsplit);
  }
}

// Round 9
// 87.308 us; speedup vs baseline: 1.1643x; 1.0443x over previous
//
#include <hip/hip_runtime.h>

#define Bn 8
#define Sn 2048
#define Cn 768
#define Hn 64
#define BS (Bn * Sn)

typedef __attribute__((ext_vector_type(8))) short bf16x8;
typedef __attribute__((ext_vector_type(4))) float f32x4;

__device__ __forceinline__ unsigned short f2bf(float x) {
  unsigned int u = __builtin_bit_cast(unsigned int, x);
  u += 0x7FFFu + ((u >> 16) & 1u);
  return (unsigned short)(u >> 16);
}

// async global->LDS DMA, 16B per lane; dest = wave-uniform base + lane*16 (linear)
__device__ __forceinline__ void gload_lds16(const void* g, void* l) {
  __builtin_amdgcn_global_load_lds(
      (const __attribute__((address_space(1))) unsigned int*)g,
      (__attribute__((address_space(3))) unsigned int*)l, 16, 0, 0);
}

// ---------------- kernel 0: W convert + transpose: W[c][h] f32 -> Wt[h][c] bf16 ----------------
__global__ __launch_bounds__(256) void wconv(const float* __restrict__ Wq,
                                             const float* __restrict__ Wk,
                                             const float* __restrict__ Wv,
                                             unsigned short* __restrict__ Wt) {
  int idx = blockIdx.x * 256 + threadIdx.x;      // 3*768*64 = 147456 total
  int mat = idx / (Cn * Hn);
  int rem = idx - mat * (Cn * Hn);
  int c = rem / Hn, h = rem - c * Hn;
  const float* W = (mat == 0) ? Wq : (mat == 1) ? Wk : Wv;
  Wt[mat * (Hn * Cn) + h * Cn + c] = f2bf(W[rem]);
}

// ---------------- kernel 1: projection, async DMA + COUNTED vmcnt (T4) ----------------
// R8's staging layout (verified conflict-free) + counted-vmcnt pipeline:
// loop c: [vmcnt(6): chunk c landed, chunk c+1 in flight] [bar] [compute c]
//         [bar] [issue chunk c+2 into buf c&1]. NO vmcnt(0) drain until last iter.
// Race-safety: issue into buf c&1 happens after barrier#2 (all waves done reading);
// chunk-c visibility: every wave's own vmcnt-wait precedes barrier#1.
__global__ __launch_bounds__(256) void proj(const float* __restrict__ q,
                                            const float* __restrict__ k,
                                            const float* __restrict__ v,
                                            const float* __restrict__ bq,
                                            const float* __restrict__ bk,
                                            const float* __restrict__ bv,
                                            const unsigned short* __restrict__ Wt,
                                            unsigned short* __restrict__ qi,
                                            unsigned short* __restrict__ ki,
                                            unsigned short* __restrict__ vi) {
  const int mat  = blockIdx.x >> 8;
  const int row0 = (blockIdx.x & 255) * 64;
  const float* X    = (mat == 0) ? q  : (mat == 1) ? k  : v;
  const float* bias = (mat == 0) ? bq : (mat == 1) ? bk : bv;
  unsigned short* Y = (mat == 0) ? qi : (mat == 1) ? ki : vi;
  const unsigned short* Wm = Wt + mat * (Hn * Cn);
  const float scale = (mat == 0) ? 0.03608439182435161f : 1.0f;  // 1/sqrt(768) folded into qi

  __shared__ __align__(16) float          Xf[2][4096];   // 2 x 16KB: [64 rows][16 slots x 4 f32]
  __shared__ __align__(16) unsigned short Wl[2][4096];   // 2 x 8KB:  [64 h][8 slots x 8 bf16]

  const int tid  = threadIdx.x;
  const int lane = tid & 63;
  const int w    = tid >> 6;
  const int col  = lane & 15;
  const int grp  = lane >> 4;

  // per-thread pre-swizzled global source pointers (chunk 0)
  const float* xsrc[4];
#pragma unroll
  for (int j = 0; j < 4; ++j) {
    int sidx = j * 256 + tid;
    int row  = sidx >> 4;
    int cf4  = (sidx & 15) ^ (row & 15);
    xsrc[j]  = X + (size_t)(row0 + row) * Cn + cf4 * 4;
  }
  const unsigned short* wsrc[2];
#pragma unroll
  for (int j = 0; j < 2; ++j) {
    int sidx = j * 256 + tid;
    int h    = sidx >> 3;
    int pd   = (sidx & 7) ^ (h & 7);
    wsrc[j]  = Wm + (size_t)h * Cn + pd * 8;
  }

  // prologue: stage chunk 0 -> buf0, chunk 1 -> buf1 (12 DMAs in flight per wave)
#pragma unroll
  for (int j = 0; j < 4; ++j) gload_lds16(xsrc[j], &Xf[0][(j * 256 + w * 64) * 4]);
#pragma unroll
  for (int j = 0; j < 2; ++j) gload_lds16(wsrc[j], &Wl[0][(j * 256 + w * 64) * 8]);
#pragma unroll
  for (int j = 0; j < 4; ++j) gload_lds16(xsrc[j] + 64, &Xf[1][(j * 256 + w * 64) * 4]);
#pragma unroll
  for (int j = 0; j < 2; ++j) gload_lds16(wsrc[j] + 64, &Wl[1][(j * 256 + w * 64) * 8]);

  f32x4 acc[4] = {};
  const int rloc = w * 16 + col;

#pragma unroll
  for (int c = 0; c < 12; ++c) {
    const int buf = c & 1;
    // wait for chunk c only; chunk c+1's 6 DMAs stay in flight (T4 counted vmcnt)
    if (c == 11) {
      asm volatile("s_waitcnt vmcnt(0)" ::: "memory");
    } else {
      asm volatile("s_waitcnt vmcnt(6)" ::: "memory");
    }
    __builtin_amdgcn_s_barrier();
    __builtin_amdgcn_sched_barrier(0);
    // compute chunk c
#pragma unroll
    for (int ks = 0; ks < 2; ++ks) {
      const int cf0 = ks * 8 + grp * 2;
      float4 a0 = *(const float4*)&Xf[buf][(rloc * 16 + (cf0 ^ col)) * 4];
      float4 a1 = *(const float4*)&Xf[buf][(rloc * 16 + ((cf0 + 1) ^ col)) * 4];
      bf16x8 av;
      av[0] = (short)f2bf(a0.x); av[1] = (short)f2bf(a0.y);
      av[2] = (short)f2bf(a0.z); av[3] = (short)f2bf(a0.w);
      av[4] = (short)f2bf(a1.x); av[5] = (short)f2bf(a1.y);
      av[6] = (short)f2bf(a1.z); av[7] = (short)f2bf(a1.w);
      const int p = ks * 4 + grp;
#pragma unroll
      for (int nf = 0; nf < 4; ++nf) {
        int h = nf * 16 + col;
        bf16x8 bfr = *(const bf16x8*)&Wl[buf][(h * 8 + (p ^ (h & 7))) * 8];
        acc[nf] = __builtin_amdgcn_mfma_f32_16x16x32_bf16(av, bfr, acc[nf], 0, 0, 0);
      }
    }
    __builtin_amdgcn_sched_barrier(0);
    __builtin_amdgcn_s_barrier();    // all waves done reading buf before re-staging it
    __builtin_amdgcn_sched_barrier(0);
    if (c < 10) {                    // issue chunk c+2 into this buf; stays in flight
#pragma unroll
      for (int j = 0; j < 4; ++j)
        gload_lds16(xsrc[j] + (c + 2) * 64, &Xf[buf][(j * 256 + w * 64) * 4]);
#pragma unroll
      for (int j = 0; j < 2; ++j)
        gload_lds16(wsrc[j] + (c + 2) * 64, &Wl[buf][(j * 256 + w * 64) * 8]);
    }
  }

  // epilogue: D layout col = lane&15, row = grp*4 + reg
#pragma unroll
  for (int nf = 0; nf < 4; ++nf) {
    int h = nf * 16 + col;
    float bb = bias[h];
#pragma unroll
    for (int r2 = 0; r2 < 4; ++r2) {
      int row = row0 + w * 16 + grp * 4 + r2;
      Y[(size_t)row * Hn + h] = f2bf((acc[nf][r2] + bb) * scale);
    }
  }
}

// ---------------- kernel 2: flash attention, optional KV split ----------------
template <int SPLIT>
__global__ __launch_bounds__(256) void attn(const unsigned short* __restrict__ qi,
                                            const unsigned short* __restrict__ ki,
                                            const unsigned short* __restrict__ vi,
                                            float* __restrict__ pacc,
                                            float* __restrict__ pm,
                                            float* __restrict__ pl,
                                            float* __restrict__ out,
                                            int tpb) {
  const int bq    = blockIdx.x & 255;
  const int split = blockIdx.x >> 8;
  const int b  = bq >> 5;
  const int s0 = (bq & 31) * 64;
  const int t0 = split * tpb;
  const unsigned short* Qb = qi + ((size_t)b * Sn + s0) * Hn;
  const unsigned short* Kb = ki + (size_t)b * Sn * Hn;
  const unsigned short* Vb = vi + (size_t)b * Sn * Hn;

  __shared__ __align__(16) unsigned char Ks[64 * 128];       // [key][dim] bf16, swizzled
  __shared__ __align__(16) unsigned char Vt[64 * 128];       // [dim][key] bf16, swizzled
  __shared__ __align__(16) unsigned char Ps[4 * 16 * 128];   // per-wave [16 q][64 key] bf16

  const int tid  = threadIdx.x;
  const int lane = tid & 63;
  const int w    = tid >> 6;
  const int col  = lane & 15;
  const int grp  = lane >> 4;

  bf16x8 qa[2];
#pragma unroll
  for (int ks2 = 0; ks2 < 2; ++ks2)
    qa[ks2] = *(const bf16x8*)(Qb + (size_t)(w * 16 + col) * Hn + ks2 * 32 + grp * 8);

  f32x4 acc[4] = {};
  float m[4], l[4];
#pragma unroll
  for (int r = 0; r < 4; ++r) { m[r] = -1e30f; l[r] = 0.0f; }

  for (int t = t0; t < t0 + tpb; ++t) {
    const unsigned short* Kt = Kb + t * 64 * Hn;
    const unsigned short* Vg = Vb + t * 64 * Hn;
    __syncthreads();  // previous tile fully consumed by all waves
    {
      int kr = tid >> 2, p = tid & 3;
      const uint4* src = (const uint4*)(Kt + kr * Hn);
      uint4 a  = src[p * 2];
      uint4 b2 = src[p * 2 + 1];
      *(uint4*)(Ks + kr * 128 + ((p * 32) ^ ((kr & 7) << 4)))        = a;
      *(uint4*)(Ks + kr * 128 + (((p * 32) + 16) ^ ((kr & 7) << 4))) = b2;
    }
    {
      int kp = tid >> 3;
      int dg = tid & 7;
      uint4 v0 = *(const uint4*)(Vg + (2 * kp) * Hn + dg * 8);
      uint4 v1 = *(const uint4*)(Vg + (2 * kp + 1) * Hn + dg * 8);
      const unsigned short* a0 = (const unsigned short*)&v0;
      const unsigned short* a1 = (const unsigned short*)&v1;
#pragma unroll
      for (int j0 = 0; j0 < 8; ++j0) {
        int j = (j0 + dg) & 7;
        int d = dg * 8 + j;
        unsigned int pk = (unsigned int)a0[j] | ((unsigned int)a1[j] << 16);
        *(unsigned int*)(Vt + d * 128 + ((4 * kp) ^ ((d & 7) << 4))) = pk;
      }
    }
    __syncthreads();
    // S = Q K^T
    f32x4 sf[4] = {};
#pragma unroll
    for (int ks2 = 0; ks2 < 2; ++ks2) {
#pragma unroll
      for (int nf = 0; nf < 4; ++nf) {
        int kr = nf * 16 + col;
        bf16x8 bfr = *(const bf16x8*)(Ks + kr * 128 + ((ks2 * 64 + grp * 16) ^ ((kr & 7) << 4)));
        sf[nf] = __builtin_amdgcn_mfma_f32_16x16x32_bf16(qa[ks2], bfr, sf[nf], 0, 0, 0);
      }
    }
    // online softmax
    float mn[4], fs[4];
#pragma unroll
    for (int r = 0; r < 4; ++r) {
      float mx = fmaxf(fmaxf(sf[0][r], sf[1][r]), fmaxf(sf[2][r], sf[3][r]));
#pragma unroll
      for (int off = 1; off < 16; off <<= 1)
        mx = fmaxf(mx, __shfl_xor(mx, off, 64));
      mn[r] = fmaxf(m[r], mx);
      fs[r] = __expf(m[r] - mn[r]);
      m[r]  = mn[r];
    }
#pragma unroll
    for (int nf = 0; nf < 4; ++nf)
#pragma unroll
      for (int r = 0; r < 4; ++r)
        sf[nf][r] = __expf(sf[nf][r] - mn[r]);
#pragma unroll
    for (int r = 0; r < 4; ++r) {
      float sm = sf[0][r] + sf[1][r] + sf[2][r] + sf[3][r];
#pragma unroll
      for (int off = 1; off < 16; off <<= 1)
        sm += __shfl_xor(sm, off, 64);
      l[r] = l[r] * fs[r] + sm;
    }
#pragma unroll
    for (int nf = 0; nf < 4; ++nf) {
#pragma unroll
      for (int r = 0; r < 4; ++r) {
        acc[nf][r] *= fs[r];
        int prow = grp * 4 + r;
        int key  = nf * 16 + col;
        *(unsigned short*)(Ps + w * 2048 + prow * 128 + ((key * 2) ^ ((prow & 7) << 4))) =
            f2bf(sf[nf][r]);
      }
    }
    // per-wave Ps: no cross-wave barrier needed before PV
#pragma unroll
    for (int kk = 0; kk < 2; ++kk) {
      bf16x8 pa = *(const bf16x8*)(Ps + w * 2048 + col * 128 +
                                   ((kk * 64 + grp * 16) ^ ((col & 7) << 4)));
#pragma unroll
      for (int nf = 0; nf < 4; ++nf) {
        int dr = nf * 16 + col;
        bf16x8 bv = *(const bf16x8*)(Vt + dr * 128 + ((kk * 64 + grp * 16) ^ ((dr & 7) << 4)));
        acc[nf] = __builtin_amdgcn_mfma_f32_16x16x32_bf16(pa, bv, acc[nf], 0, 0, 0);
      }
    }
  }
  // epilogue
  if (SPLIT) {
    const size_t sb = (size_t)split * BS + (size_t)b * Sn;
#pragma unroll
    for (int nf = 0; nf < 4; ++nf) {
#pragma unroll
      for (int r = 0; r < 4; ++r) {
        int row = s0 + w * 16 + grp * 4 + r;
        pacc[(sb + row) * Hn + nf * 16 + col] = acc[nf][r];
      }
    }
    if (col == 0) {
#pragma unroll
      for (int r = 0; r < 4; ++r) {
        int row = s0 + w * 16 + grp * 4 + r;
        pm[sb + row] = m[r];
        pl[sb + row] = l[r];
      }
    }
  } else {
#pragma unroll
    for (int nf = 0; nf < 4; ++nf) {
#pragma unroll
      for (int r = 0; r < 4; ++r) {
        int row = s0 + w * 16 + grp * 4 + r;
        out[((size_t)b * Sn + row) * Hn + nf * 16 + col] = acc[nf][r] / l[r];
      }
    }
  }
}

// ---------------- kernel 3: combine attn split partials ----------------
__global__ __launch_bounds__(256) void combine(const float* __restrict__ pacc,
                                               const float* __restrict__ pm,
                                               const float* __restrict__ pl,
                                               float* __restrict__ out,
                                               int nsplit) {
  int gid = blockIdx.x * 256 + threadIdx.x;
  int gr  = gid >> 4;          // global row in [0, B*S)
  int dq  = (gid & 15) * 4;    // dim quad
  float M = -1e30f;
  for (int s = 0; s < nsplit; ++s) M = fmaxf(M, pm[(size_t)s * BS + gr]);
  float L = 0.0f;
  float4 o = make_float4(0.f, 0.f, 0.f, 0.f);
  for (int s = 0; s < nsplit; ++s) {
    float wgt = __expf(pm[(size_t)s * BS + gr] - M);
    L += pl[(size_t)s * BS + gr] * wgt;
    float4 p = *(const float4*)(pacc + ((size_t)s * BS + gr) * Hn + dq);
    o.x += p.x * wgt; o.y += p.y * wgt; o.z += p.z * wgt; o.w += p.w * wgt;
  }
  float inv = 1.0f / L;
  float4 r = make_float4(o.x * inv, o.y * inv, o.z * inv, o.w * inv);
  *(float4*)(out + (size_t)gr * Hn + dq) = r;
}

extern "C" void kernel_launch(void* const* d_in, const int* in_sizes, int n_in,
                              void* d_out, int out_size, void* d_ws, size_t ws_size,
                              hipStream_t stream) {
  const float* q  = (const float*)d_in[0];
  const float* k  = (const float*)d_in[1];
  const float* v  = (const float*)d_in[2];
  const float* Wq = (const float*)d_in[3];
  const float* bq = (const float*)d_in[4];
  const float* Wk = (const float*)d_in[5];
  const float* bk = (const float*)d_in[6];
  const float* Wv = (const float*)d_in[7];
  const float* bv = (const float*)d_in[8];
  float* out = (float*)d_out;

  unsigned short* Wt = (unsigned short*)d_ws;            // [3][64][768] bf16
  unsigned short* qi = Wt + 3 * Hn * Cn;                 // bf16, pre-scaled by 1/sqrt(C)
  unsigned short* ki = qi + (size_t)BS * Hn;
  unsigned short* vi = ki + (size_t)BS * Hn;
  float* pacc = (float*)(vi + (size_t)BS * Hn);

  const size_t base_bytes = (size_t)(3 * Hn * Cn + 3 * (size_t)BS * Hn) * 2;
  const size_t avail = (ws_size > base_bytes) ? ws_size - base_bytes : 0;

  int nsplit = 4;
  while (nsplit > 1 &&
         (size_t)nsplit * ((size_t)BS * Hn * 4 + 2 * (size_t)BS * 4) > avail)
    nsplit >>= 1;
  bool direct = ((size_t)nsplit * ((size_t)BS * Hn * 4 + 2 * (size_t)BS * 4) > avail);

  float* pm = pacc + (size_t)nsplit * BS * Hn;
  float* pl = pm + (size_t)nsplit * BS;

  wconv<<<dim3((3 * Cn * Hn) / 256), dim3(256), 0, stream>>>(Wq, Wk, Wv, Wt);
  proj<<<dim3(768), dim3(256), 0, stream>>>(q, k, v, bq, bk, bv, Wt, qi, ki, vi);
  if (direct) {
    attn<0><<<dim3(256), dim3(256), 0, stream>>>(qi, ki, vi, nullptr, nullptr, nullptr, out, 32);
  } else {
    attn<1><<<dim3(256 * nsplit), dim3(256), 0, stream>>>(qi, ki, vi, pacc, pm, pl, nullptr,
                                                          32 / nsplit);
    combine<<<dim3(BS * 16 / 256), dim3(256), 0, stream>>>(pacc, pm, pl, out, nsplit);
  }
}